// Round 12
// baseline (304.204 us; speedup 1.0000x reference)
//
#include <hip/hip_runtime.h>
#include <stdint.h>

// Problem constants
#define BB 4
#define TT 2048
#define CC 1024
#define HH 16
#define DD 64
#define MM (BB * TT)   // 8192 rows for QKV projection

typedef unsigned short u16;
typedef unsigned int   u32;
typedef __attribute__((ext_vector_type(8))) short short8;   // 8 bf16 (4 VGPRs)
typedef _Float16 half8  __attribute__((ext_vector_type(8)));
typedef __fp16   fp16x2 __attribute__((ext_vector_type(2)));
typedef __attribute__((ext_vector_type(4))) float f32x4;    // MFMA C/D
typedef __attribute__((ext_vector_type(4))) unsigned short u16x4;
typedef __attribute__((ext_vector_type(4))) unsigned int u32x4;

#if __has_builtin(__builtin_amdgcn_exp2f)
#define EXP2(x) __builtin_amdgcn_exp2f(x)
#else
#define EXP2(x) __expf(0.69314718055994531f * (x))
#endif

__device__ inline u16 f2bf(float f) {
    union { float f; unsigned u; } v; v.f = f;
    unsigned r = 0x7fffu + ((v.u >> 16) & 1u);   // RNE
    return (u16)((v.u + r) >> 16);
}
__device__ inline u16 f2h(float f) {
    union { _Float16 h; u16 u; } c; c.h = (_Float16)f; return c.u;
}
__device__ inline u32 pkh(float a, float b) {   // pack 2 f32 -> f16x2 (v_cvt_pkrtz)
    union { fp16x2 h; u32 u; } c;
    c.h = __builtin_amdgcn_cvt_pkrtz(a, b);
    return c.u;
}
__device__ inline u32 pkmask(int a, int b) {    // {0,1}x2 -> f16-pair AND mask
    return ((u32)(-a) & 0xFFFFu) | ((u32)(-b) << 16);
}

// ---------------------------------------------------------------- convert (fused)
// Also pre-packs the attention mask into per-(b,tile,lq) f16-pair AND masks so
// the attn inner loop does ZERO mask VALU.
#define NX (MM * CC / 4)   // x float4 count
#define NW (CC * CC / 4)   // one W float4 count
#define NPM (BB * 1024)    // packed-mask u32 count: [b][kt][lq][j]
__global__ void cvt_all(const float* __restrict__ x,  const float* __restrict__ Wq,
                        const float* __restrict__ Wk, const float* __restrict__ Wv,
                        const int* __restrict__ mask,
                        u16* __restrict__ xb, u16* __restrict__ Wb,
                        u32* __restrict__ pm) {
    int i = blockIdx.x * blockDim.x + threadIdx.x;
    if (i >= NX + 3 * NW) {
        int idx = i - (NX + 3 * NW);
        if (idx < NPM) {
            int b = idx >> 10, r = idx & 1023;
            int kt = r >> 5, lq = (r >> 3) & 3, j = r & 7;
            int key = kt * 64 + (j >> 2) * 32 + ((j >> 1) & 1) * 16 + lq * 4 + (j & 1) * 2;
            pm[idx] = pkmask(mask[b * TT + key], mask[b * TT + key + 1]);
        }
        return;
    }
    const float* src; u16* dst; int j;
    if (i < NX)               { src = x;  dst = xb;                       j = i; }
    else if (i < NX + NW)     { src = Wq; dst = Wb;                       j = i - NX; }
    else if (i < NX + 2 * NW) { src = Wk; dst = Wb + (size_t)CC * CC;     j = i - NX - NW; }
    else                      { src = Wv; dst = Wb + (size_t)2 * CC * CC; j = i - NX - 2 * NW; }
    float4 v = ((const float4*)src)[j];
    u16x4 o;
    o.x = f2bf(v.x); o.y = f2bf(v.y); o.z = f2bf(v.z); o.w = f2bf(v.w);
    ((u16x4*)dst)[j] = o;
}

// ---------------------------------------------------------------- QKV GEMM
// C[m][n] = sum_k x[m][k] * W[n][k]  (+bias, *scale); outputs f16.
// z<2 (Q,K): computed as W·x^T (A=W) so each lane holds 4 consecutive d -> 8B stores.
// z==2 (V): computed as x·W^T (A=x); stored into [B,H,D,T] with the attn sigma
//           key-permutation PRE-APPLIED within each 32-key block.
// Q pre-scaled by (1/sqrt(D)) * log2(e) so attention uses raw exp2.
// XCD-aware remap (r8, verified −10us): each XCD owns a contiguous 8-m-block
// slice (2 MB x rows, L2-resident) for all (n,z). No setprio here (m190:
// setprio hurts barrier-lockstep GEMM).
__global__ void qkv_gemm(const u16* __restrict__ xb, const u16* __restrict__ Wb,
                         const float* __restrict__ bq, const float* __restrict__ bk,
                         const float* __restrict__ bv,
                         u16* __restrict__ Qh, u16* __restrict__ Kh, u16* __restrict__ Vt)
{
    // flat id with grid (8,64,3): f0 % 8 == blockIdx.x -> xcd
    const int f0  = blockIdx.x + 8 * (blockIdx.y + 64 * blockIdx.z);
    const int xcd = f0 & 7, g = f0 >> 3;          // g in [0,192)
    const int mi  = g & 7, n_ = (g >> 3) & 7;
    const int z   = g >> 6;                       // 0..2
    const int m0  = (xcd * 8 + mi) * 128, n0 = n_ * 128;

    const u16* W = Wb + (size_t)z * CC * CC;
    const float* bias = (z == 0) ? bq : ((z == 1) ? bk : bv);
    const float scale = (z == 0) ? 0.18033688011112042f : 1.0f;  // 0.125*log2(e) for Q

    __shared__ __align__(16) u16 As[128][32];   // x rows
    __shared__ __align__(16) u16 Bs[128][32];   // W rows

    const int tid = threadIdx.x;
    const int l  = tid & 63, w = tid >> 6;
    const int wm = w >> 1,  wn = w & 1;
    const int lr = l & 15,  lq = l >> 4;

    f32x4 acc[4][4] = {};

    // A operand: x for V (z==2), W for Q/K
    const u16* aLDS = (z == 2) ? &As[0][0] : &Bs[0][0];
    const u16* bLDS = (z == 2) ? &Bs[0][0] : &As[0][0];

    for (int kt = 0; kt < CC; kt += 32) {
        __syncthreads();
        #pragma unroll
        for (int r = 0; r < 2; ++r) {
            int c   = (r * 4 + w) * 64 + l;
            int row = c >> 2, kc = c & 3;
            const u16* ga = xb + (size_t)(m0 + row) * CC + kt + kc * 8;
            __builtin_amdgcn_global_load_lds(
                (const __attribute__((address_space(1))) void*)ga,
                (__attribute__((address_space(3))) void*)(&As[0][0] + (size_t)c * 8), 16, 0, 0);
            const u16* gb = W + (size_t)(n0 + row) * CC + kt + kc * 8;
            __builtin_amdgcn_global_load_lds(
                (const __attribute__((address_space(1))) void*)gb,
                (__attribute__((address_space(3))) void*)(&Bs[0][0] + (size_t)c * 8), 16, 0, 0);
        }
        __syncthreads();

        short8 af[4], bfr[4];
        #pragma unroll
        for (int mi2 = 0; mi2 < 4; ++mi2)
            af[mi2] = *(const short8*)(aLDS + (size_t)(wm * 64 + mi2 * 16 + lr) * 32 + lq * 8);
        #pragma unroll
        for (int ni = 0; ni < 4; ++ni)
            bfr[ni] = *(const short8*)(bLDS + (size_t)(wn * 64 + ni * 16 + lr) * 32 + lq * 8);
        #pragma unroll
        for (int mi2 = 0; mi2 < 4; ++mi2)
            #pragma unroll
            for (int ni = 0; ni < 4; ++ni)
                acc[mi2][ni] = __builtin_amdgcn_mfma_f32_16x16x32_bf16(
                    af[mi2], bfr[ni], acc[mi2][ni], 0, 0, 0);
    }

    // epilogue: C/D layout col=lane&15, row=(lane>>4)*4+reg
    if (z == 2) {
        // rows = x (t), cols = W (d). 4 consecutive t per reg group.
        #pragma unroll
        for (int ni = 0; ni < 4; ++ni) {
            int n = n0 + wn * 64 + ni * 16 + lr;
            float bvv = bias[n];
            int h = n >> 6, d = n & 63;
            #pragma unroll
            for (int mi2 = 0; mi2 < 4; ++mi2) {
                int mbase = m0 + wm * 64 + mi2 * 16 + lq * 4;
                int b = mbase >> 11, t0 = mbase & (TT - 1);
                // sigma pre-permutation within the 32-key block
                int gk  = (t0 >> 2) & 7;
                int t0p = (t0 & ~31) | (((gk & 3) << 3) | ((gk >> 2) << 2));
                u16x4 pkv;
                #pragma unroll
                for (int r = 0; r < 4; ++r)
                    pkv[r] = f2h(acc[mi2][ni][r] + bvv);
                *(u16x4*)&Vt[((size_t)(b * HH + h) * DD + d) * TT + t0p] = pkv;
            }
        }
    } else {
        // rows = W (n -> h,d), cols = x (t). 4 consecutive d per reg group.
        u16* out = (z == 0) ? Qh : Kh;
        #pragma unroll
        for (int mi2 = 0; mi2 < 4; ++mi2) {
            int nb = n0 + wm * 64 + mi2 * 16 + lq * 4;
            float4 b4 = *(const float4*)&bias[nb];
            int h = nb >> 6, d0 = nb & 63;
            #pragma unroll
            for (int ni = 0; ni < 4; ++ni) {
                int m = m0 + wn * 64 + ni * 16 + lr;
                int b = m >> 11, t = m & (TT - 1);
                u16x4 pkv;
                pkv.x = f2h((acc[mi2][ni][0] + b4.x) * scale);
                pkv.y = f2h((acc[mi2][ni][1] + b4.y) * scale);
                pkv.z = f2h((acc[mi2][ni][2] + b4.z) * scale);
                pkv.w = f2h((acc[mi2][ni][3] + b4.w) * scale);
                *(u16x4*)&out[((size_t)(b * HH + h) * TT + t) * DD + d0] = pkv;
            }
        }
    }
}

// ---------------------------------------------------------------- attention
// 1 block per (b, h, 128 q-rows). 4 waves x 32 q-rows. 64-key tiles, double-
// buffered LDS, XCD-aware swizzle (K/V L2-resident: FETCH 24.6 MB).
// This is the r8 kernel (best: attn 80.2us) + ONE isolated change: s_setprio(1)
// around the QK and PV MFMA clusters (T5 precedent: attn +4-7%, m191). r9
// (phase rotation) and r10 (PV-first pipeline) both regressed and are reverted.
// launch_bounds(256,4): 64-VGPR cap, 4 blocks/CU — the proven-clean config.
__global__ __launch_bounds__(256, 4)
void attn_kernel(const u16* __restrict__ Qh, const u16* __restrict__ Kh,
                 const u16* __restrict__ Vt, const u32* __restrict__ pm,
                 float* __restrict__ out)
{
    // XCD-aware swizzle (1024 blocks, 8 XCDs, dispatch round-robins f&7)
    const int f   = blockIdx.x + (TT / 128) * (blockIdx.y + HH * blockIdx.z);
    const int xcd = f & 7, g = f >> 3;
    const int bh  = xcd * 8 + (g >> 4);   // 0..63, contiguous per XCD
    const int qt  = g & 15;               // 0..15
    const int b   = bh >> 4, h = bh & 15;

    const int tid = threadIdx.x;
    const int l  = tid & 63, w = tid >> 6;
    const int lr = l & 15,  lq = l >> 4;

    __shared__ __align__(16) u16 Ks[2][64][72];     // [buf][key][d], 144B rows
    __shared__ __align__(16) u16 Vs[2][2][64][40];  // [buf][half][d][sigma-slot]

    const size_t base = (size_t)(b * HH + h) * TT * DD;   // TT*DD == DD*TT
    const int q0 = qt * 128 + w * 32;

    // Q B-fragments (f16; 1/sqrt(D)*log2e pre-folded): B[n=q=lr][k=c*32+lq*8+j]
    half8 qf[2][2];
    #pragma unroll
    for (int qg = 0; qg < 2; ++qg)
        #pragma unroll
        for (int c = 0; c < 2; ++c)
            qf[qg][c] = *(const half8*)(Qh + base + (size_t)(q0 + qg * 16 + lr) * DD
                                        + c * 32 + lq * 8);

    // staging geometry (per 64-key tile each thread: 2 K half8s + 2 V half8s)
    const int kk = tid >> 3, dc = tid & 7;          // K: key 0..31, d-chunk 0..7
    u16* k_dst0 = &Ks[0][kk][dc * 8];
    const u16* k_base = Kh + base + (size_t)kk * DD + dc * 8;
    const int vd = tid >> 2, vck = tid & 3;         // V^T: d-row 0..63, slot-chunk 0..3
    u16* v_dst0 = &Vs[0][0][vd][vck * 8];           // sigma pre-applied in Vt
    const u16* v_base = Vt + base + (size_t)vd * TT + vck * 8;
    const u32* pm_base = pm + b * 1024 + lq * 8;    // [kt][lq][8]

    const int VHALF = 64 * 40;        // u16 stride between halves
    const int VBUF  = 2 * VHALF;      // u16 stride between buffers
    const int KHALF = 32 * 72;
    const int KBUF  = 64 * 72;

    union { u32 u[4]; half8 h; } one_u;
    one_u.u[0] = one_u.u[1] = one_u.u[2] = one_u.u[3] = 0x3C003C00u;   // f16 1.0 x8
    const half8 ones = one_u.h;

    // preload tile 0 into buffer 0 (straight copies)
    {
        half8 k0 = *(const half8*)k_base;
        half8 k1 = *(const half8*)(k_base + 32 * DD);
        half8 v0 = *(const half8*)v_base;
        half8 v1 = *(const half8*)(v_base + 32);
        *(half8*)k_dst0 = k0;
        *(half8*)(k_dst0 + KHALF) = k1;
        *(half8*)v_dst0 = v0;
        *(half8*)(v_dst0 + VHALF) = v1;
    }

    f32x4 o[2][5] = {};   // [qg][dg 0..3 = O d-groups, dg 4 = softmax denom l]

    const int NT = TT / 64;   // 32
    __syncthreads();

    for (int kt = 0; kt < NT; ++kt) {
        const int p = kt & 1;
        // register prefetch of next tile (overlaps compute)
        int ktn = (kt + 1 < NT) ? kt + 1 : NT - 1;
        const u16* kp = k_base + (size_t)ktn * 64 * DD;
        half8 kreg0 = *(const half8*)kp;
        half8 kreg1 = *(const half8*)(kp + 32 * DD);
        const u16* vp = v_base + ktn * 64;
        half8 vreg0 = *(const half8*)vp;
        half8 vreg1 = *(const half8*)(vp + 32);
        // current tile's packed masks (2 dwordx4 loads, zero VALU)
        u32x4 am0 = *(const u32x4*)(pm_base + kt * 32);
        u32x4 am1 = *(const u32x4*)(pm_base + kt * 32 + 4);

        // ---- K A-fragments: A[m=key=kg*16+lr][k=c*32+lq*8+j]
        half8 kf[4][2];
        #pragma unroll
        for (int kg = 0; kg < 4; ++kg)
            #pragma unroll
            for (int c = 0; c < 2; ++c)
                kf[kg][c] = *(const half8*)&Ks[p][kg * 16 + lr][c * 32 + lq * 8];

        // ---- S^T = K Q^T : lane holds keys kg*16+lq*4+r, q = qg*16+lr
        f32x4 s[4][2];
        __builtin_amdgcn_s_setprio(1);
        #pragma unroll
        for (int kg = 0; kg < 4; ++kg)
            #pragma unroll
            for (int qg = 0; qg < 2; ++qg) {
                f32x4 zz = {};
                zz = __builtin_amdgcn_mfma_f32_16x16x32_f16(kf[kg][0], qf[qg][0], zz, 0, 0, 0);
                zz = __builtin_amdgcn_mfma_f32_16x16x32_f16(kf[kg][1], qf[qg][1], zz, 0, 0, 0);
                s[kg][qg] = zz;
            }
        __builtin_amdgcn_s_setprio(0);

        // ---- P = exp2(S) & mask, packed in-lane into PV A-fragments (sigma layout)
        half8 pf[2][2];   // [half][qg]
        #pragma unroll
        for (int hf = 0; hf < 2; ++hf) {
            const u32x4 am = hf ? am1 : am0;
            #pragma unroll
            for (int qg = 0; qg < 2; ++qg) {
                u32x4 pk;
                pk[0] = pkh(EXP2(s[2*hf][qg][0]),   EXP2(s[2*hf][qg][1]))   & am[0];
                pk[1] = pkh(EXP2(s[2*hf][qg][2]),   EXP2(s[2*hf][qg][3]))   & am[1];
                pk[2] = pkh(EXP2(s[2*hf+1][qg][0]), EXP2(s[2*hf+1][qg][1])) & am[2];
                pk[3] = pkh(EXP2(s[2*hf+1][qg][2]), EXP2(s[2*hf+1][qg][3])) & am[3];
                pf[hf][qg] = (half8&)pk;
            }
        }

        // ---- O += P V  (per half; l via register ones B-fragment)
        __builtin_amdgcn_s_setprio(1);
        #pragma unroll
        for (int hf = 0; hf < 2; ++hf) {
            #pragma unroll
            for (int dg = 0; dg < 4; ++dg) {
                half8 vf = *(const half8*)&Vs[p][hf][dg * 16 + lr][lq * 8];
                #pragma unroll
                for (int qg = 0; qg < 2; ++qg)
                    o[qg][dg] = __builtin_amdgcn_mfma_f32_16x16x32_f16(pf[hf][qg], vf, o[qg][dg], 0, 0, 0);
            }
            #pragma unroll
            for (int qg = 0; qg < 2; ++qg)
                o[qg][4] = __builtin_amdgcn_mfma_f32_16x16x32_f16(pf[hf][qg], ones, o[qg][4], 0, 0, 0);
        }
        __builtin_amdgcn_s_setprio(0);

        // ---- write prefetched tile into the other buffer (straight copies)
        u16* kd = k_dst0 + (p ^ 1) * KBUF;
        *(half8*)kd = kreg0;
        *(half8*)(kd + KHALF) = kreg1;
        u16* vdst = v_dst0 + (p ^ 1) * VBUF;
        *(half8*)vdst = vreg0;
        *(half8*)(vdst + VHALF) = vreg1;
        __syncthreads();
    }

    // ---- epilogue: O / l, write fp32 [B,T,C]
    #pragma unroll
    for (int qg = 0; qg < 2; ++qg)
        #pragma unroll
        for (int r = 0; r < 4; ++r) {
            float inv = 1.f / o[qg][4][r];
            int t = q0 + qg * 16 + lq * 4 + r;
            float* op = out + (size_t)(b * TT + t) * CC + h * DD;
            #pragma unroll
            for (int dg = 0; dg < 4; ++dg)
                op[dg * 16 + lr] = o[qg][dg][r] * inv;
        }
}

// ---------------------------------------------------------------- launch
extern "C" void kernel_launch(void* const* d_in, const int* in_sizes, int n_in,
                              void* d_out, int out_size, void* d_ws, size_t ws_size,
                              hipStream_t stream) {
    const float* x    = (const float*)d_in[0];
    const int*   mask = (const int*)d_in[1];
    const float* Wq   = (const float*)d_in[2];
    const float* bq   = (const float*)d_in[3];
    const float* Wk   = (const float*)d_in[4];
    const float* bk   = (const float*)d_in[5];
    const float* Wv   = (const float*)d_in[6];
    const float* bv   = (const float*)d_in[7];
    float* out = (float*)d_out;

    // workspace layout
    u16* xb = (u16*)d_ws;                              // bf16 [8192][1024]
    u16* Wb = xb + (size_t)MM * CC;                    // bf16 [3][1024][1024]
    u16* Qh = Wb + (size_t)3 * CC * CC;                // f16 [B,H,T,D]
    u16* Kh = Qh + (size_t)MM * CC;                    // f16 [B,H,T,D]
    u16* Vt = Kh + (size_t)MM * CC;                    // f16 [B,H,D,T], sigma-permuted keys
    u32* pm = (u32*)(Vt + (size_t)MM * CC);            // packed masks [B][32][4][8]

    {
        int total = NX + 3 * NW + NPM;
        cvt_all<<<(total + 255) / 256, 256, 0, stream>>>(x, Wq, Wk, Wv, mask, xb, Wb, pm);
    }

    qkv_gemm<<<dim3(8, 64, 3), 256, 0, stream>>>(xb, Wb, bq, bk, bv, Qh, Kh, Vt);

    attn_kernel<<<dim3(TT / 128, HH, BB), 256, 0, stream>>>(Qh, Kh, Vt, pm, out);
}

// Round 13
// 239.082 us; speedup vs baseline: 1.2724x; 1.2724x over previous
//
#include <hip/hip_runtime.h>
#include <stdint.h>

// Problem constants
#define BB 4
#define TT 2048
#define CC 1024
#define HH 16
#define DD 64
#define MM (BB * TT)   // 8192 rows for QKV projection

typedef unsigned short u16;
typedef unsigned int   u32;
typedef __attribute__((ext_vector_type(8))) short short8;   // 8 bf16 (4 VGPRs)
typedef _Float16 half8  __attribute__((ext_vector_type(8)));
typedef __fp16   fp16x2 __attribute__((ext_vector_type(2)));
typedef __attribute__((ext_vector_type(4))) float f32x4;    // MFMA C/D
typedef __attribute__((ext_vector_type(4))) unsigned short u16x4;
typedef __attribute__((ext_vector_type(4))) unsigned int u32x4;

#if __has_builtin(__builtin_amdgcn_exp2f)
#define EXP2(x) __builtin_amdgcn_exp2f(x)
#else
#define EXP2(x) __expf(0.69314718055994531f * (x))
#endif

__device__ inline u16 f2bf(float f) {
    union { float f; unsigned u; } v; v.f = f;
    unsigned r = 0x7fffu + ((v.u >> 16) & 1u);   // RNE
    return (u16)((v.u + r) >> 16);
}
__device__ inline u16 f2h(float f) {
    union { _Float16 h; u16 u; } c; c.h = (_Float16)f; return c.u;
}
__device__ inline u32 pkh(float a, float b) {   // pack 2 f32 -> f16x2 (v_cvt_pkrtz)
    union { fp16x2 h; u32 u; } c;
    c.h = __builtin_amdgcn_cvt_pkrtz(a, b);
    return c.u;
}
__device__ inline u32 pkmask(int a, int b) {    // {0,1}x2 -> f16-pair AND mask
    return ((u32)(-a) & 0xFFFFu) | ((u32)(-b) << 16);
}

// ---------------------------------------------------------------- convert (fused)
// Also pre-packs the attention mask into per-(b,tile,lq) f16-pair AND masks so
// the attn inner loop does ZERO mask VALU.
#define NX (MM * CC / 4)   // x float4 count
#define NW (CC * CC / 4)   // one W float4 count
#define NPM (BB * 1024)    // packed-mask u32 count: [b][kt][lq][j]
__global__ void cvt_all(const float* __restrict__ x,  const float* __restrict__ Wq,
                        const float* __restrict__ Wk, const float* __restrict__ Wv,
                        const int* __restrict__ mask,
                        u16* __restrict__ xb, u16* __restrict__ Wb,
                        u32* __restrict__ pm) {
    int i = blockIdx.x * blockDim.x + threadIdx.x;
    if (i >= NX + 3 * NW) {
        int idx = i - (NX + 3 * NW);
        if (idx < NPM) {
            int b = idx >> 10, r = idx & 1023;
            int kt = r >> 5, lq = (r >> 3) & 3, j = r & 7;
            int key = kt * 64 + (j >> 2) * 32 + ((j >> 1) & 1) * 16 + lq * 4 + (j & 1) * 2;
            pm[idx] = pkmask(mask[b * TT + key], mask[b * TT + key + 1]);
        }
        return;
    }
    const float* src; u16* dst; int j;
    if (i < NX)               { src = x;  dst = xb;                       j = i; }
    else if (i < NX + NW)     { src = Wq; dst = Wb;                       j = i - NX; }
    else if (i < NX + 2 * NW) { src = Wk; dst = Wb + (size_t)CC * CC;     j = i - NX - NW; }
    else                      { src = Wv; dst = Wb + (size_t)2 * CC * CC; j = i - NX - 2 * NW; }
    float4 v = ((const float4*)src)[j];
    u16x4 o;
    o.x = f2bf(v.x); o.y = f2bf(v.y); o.z = f2bf(v.z); o.w = f2bf(v.w);
    ((u16x4*)dst)[j] = o;
}

// ---------------------------------------------------------------- QKV GEMM
// C[m][n] = sum_k x[m][k] * W[n][k]  (+bias, *scale); outputs f16.
// z<2 (Q,K): computed as W·x^T (A=W) so each lane holds 4 consecutive d -> 8B stores.
// z==2 (V): computed as x·W^T (A=x); stored into [B,H,D,T] with the attn sigma
//           key-permutation PRE-APPLIED within each 32-key block.
// Q pre-scaled by (1/sqrt(D)) * log2(e) so attention uses raw exp2.
// XCD-aware remap (r8, verified −10us): each XCD owns a contiguous 8-m-block
// slice (2 MB x rows, L2-resident) for all (n,z).
__global__ void qkv_gemm(const u16* __restrict__ xb, const u16* __restrict__ Wb,
                         const float* __restrict__ bq, const float* __restrict__ bk,
                         const float* __restrict__ bv,
                         u16* __restrict__ Qh, u16* __restrict__ Kh, u16* __restrict__ Vt)
{
    // flat id with grid (8,64,3): f0 % 8 == blockIdx.x -> xcd
    const int f0  = blockIdx.x + 8 * (blockIdx.y + 64 * blockIdx.z);
    const int xcd = f0 & 7, g = f0 >> 3;          // g in [0,192)
    const int mi  = g & 7, n_ = (g >> 3) & 7;
    const int z   = g >> 6;                       // 0..2
    const int m0  = (xcd * 8 + mi) * 128, n0 = n_ * 128;

    const u16* W = Wb + (size_t)z * CC * CC;
    const float* bias = (z == 0) ? bq : ((z == 1) ? bk : bv);
    const float scale = (z == 0) ? 0.18033688011112042f : 1.0f;  // 0.125*log2(e) for Q

    __shared__ __align__(16) u16 As[128][32];   // x rows
    __shared__ __align__(16) u16 Bs[128][32];   // W rows

    const int tid = threadIdx.x;
    const int l  = tid & 63, w = tid >> 6;
    const int wm = w >> 1,  wn = w & 1;
    const int lr = l & 15,  lq = l >> 4;

    f32x4 acc[4][4] = {};

    // A operand: x for V (z==2), W for Q/K
    const u16* aLDS = (z == 2) ? &As[0][0] : &Bs[0][0];
    const u16* bLDS = (z == 2) ? &Bs[0][0] : &As[0][0];

    for (int kt = 0; kt < CC; kt += 32) {
        __syncthreads();
        #pragma unroll
        for (int r = 0; r < 2; ++r) {
            int c   = (r * 4 + w) * 64 + l;
            int row = c >> 2, kc = c & 3;
            const u16* ga = xb + (size_t)(m0 + row) * CC + kt + kc * 8;
            __builtin_amdgcn_global_load_lds(
                (const __attribute__((address_space(1))) void*)ga,
                (__attribute__((address_space(3))) void*)(&As[0][0] + (size_t)c * 8), 16, 0, 0);
            const u16* gb = W + (size_t)(n0 + row) * CC + kt + kc * 8;
            __builtin_amdgcn_global_load_lds(
                (const __attribute__((address_space(1))) void*)gb,
                (__attribute__((address_space(3))) void*)(&Bs[0][0] + (size_t)c * 8), 16, 0, 0);
        }
        __syncthreads();

        short8 af[4], bfr[4];
        #pragma unroll
        for (int mi2 = 0; mi2 < 4; ++mi2)
            af[mi2] = *(const short8*)(aLDS + (size_t)(wm * 64 + mi2 * 16 + lr) * 32 + lq * 8);
        #pragma unroll
        for (int ni = 0; ni < 4; ++ni)
            bfr[ni] = *(const short8*)(bLDS + (size_t)(wn * 64 + ni * 16 + lr) * 32 + lq * 8);
        #pragma unroll
        for (int mi2 = 0; mi2 < 4; ++mi2)
            #pragma unroll
            for (int ni = 0; ni < 4; ++ni)
                acc[mi2][ni] = __builtin_amdgcn_mfma_f32_16x16x32_bf16(
                    af[mi2], bfr[ni], acc[mi2][ni], 0, 0, 0);
    }

    // epilogue: C/D layout col=lane&15, row=(lane>>4)*4+reg
    if (z == 2) {
        // rows = x (t), cols = W (d). 4 consecutive t per reg group.
        #pragma unroll
        for (int ni = 0; ni < 4; ++ni) {
            int n = n0 + wn * 64 + ni * 16 + lr;
            float bvv = bias[n];
            int h = n >> 6, d = n & 63;
            #pragma unroll
            for (int mi2 = 0; mi2 < 4; ++mi2) {
                int mbase = m0 + wm * 64 + mi2 * 16 + lq * 4;
                int b = mbase >> 11, t0 = mbase & (TT - 1);
                // sigma pre-permutation within the 32-key block
                int gk  = (t0 >> 2) & 7;
                int t0p = (t0 & ~31) | (((gk & 3) << 3) | ((gk >> 2) << 2));
                u16x4 pkv;
                #pragma unroll
                for (int r = 0; r < 4; ++r)
                    pkv[r] = f2h(acc[mi2][ni][r] + bvv);
                *(u16x4*)&Vt[((size_t)(b * HH + h) * DD + d) * TT + t0p] = pkv;
            }
        }
    } else {
        // rows = W (n -> h,d), cols = x (t). 4 consecutive d per reg group.
        u16* out = (z == 0) ? Qh : Kh;
        #pragma unroll
        for (int mi2 = 0; mi2 < 4; ++mi2) {
            int nb = n0 + wm * 64 + mi2 * 16 + lq * 4;
            float4 b4 = *(const float4*)&bias[nb];
            int h = nb >> 6, d0 = nb & 63;
            #pragma unroll
            for (int ni = 0; ni < 4; ++ni) {
                int m = m0 + wn * 64 + ni * 16 + lr;
                int b = m >> 11, t = m & (TT - 1);
                u16x4 pkv;
                pkv.x = f2h((acc[mi2][ni][0] + b4.x) * scale);
                pkv.y = f2h((acc[mi2][ni][1] + b4.y) * scale);
                pkv.z = f2h((acc[mi2][ni][2] + b4.z) * scale);
                pkv.w = f2h((acc[mi2][ni][3] + b4.w) * scale);
                *(u16x4*)&out[((size_t)(b * HH + h) * TT + t) * DD + d0] = pkv;
            }
        }
    }
}

// ---------------------------------------------------------------- attention
// 1 block per (b, h, 128 q-rows). 4 waves x 32 q-rows. 64-key tiles, double-
// buffered LDS, XCD-aware swizzle (K/V L2-resident: FETCH 24.6 MB).
// FINAL: exact r8 kernel (session best, attn 80.2us). Reverted grafts:
//   r9 phase rotation (null, +2us addr overhead), r10 PV-first pipeline
//   (-7us: occupancy misconfig + no critical-path gain), r12 setprio
//   (spill: setprio regions pin prefetch live ranges past the 64-VGPR
//   occupancy tier -> compiler spills to scratch, WRITE 33->182 MB).
// V staging is a straight half8 copy (sigma pre-applied in qkv_gemm);
// masks pre-packed in pm (zero mask VALU); loop body inline, clamped
// prefetch — the proven-clean 64-VGPR shape.
__global__ __launch_bounds__(256, 4)
void attn_kernel(const u16* __restrict__ Qh, const u16* __restrict__ Kh,
                 const u16* __restrict__ Vt, const u32* __restrict__ pm,
                 float* __restrict__ out)
{
    // XCD-aware swizzle (1024 blocks, 8 XCDs, dispatch round-robins f&7)
    const int f   = blockIdx.x + (TT / 128) * (blockIdx.y + HH * blockIdx.z);
    const int xcd = f & 7, g = f >> 3;
    const int bh  = xcd * 8 + (g >> 4);   // 0..63, contiguous per XCD
    const int qt  = g & 15;               // 0..15
    const int b   = bh >> 4, h = bh & 15;

    const int tid = threadIdx.x;
    const int l  = tid & 63, w = tid >> 6;
    const int lr = l & 15,  lq = l >> 4;

    __shared__ __align__(16) u16 Ks[2][64][72];     // [buf][key][d], 144B rows
    __shared__ __align__(16) u16 Vs[2][2][64][40];  // [buf][half][d][sigma-slot]

    const size_t base = (size_t)(b * HH + h) * TT * DD;   // TT*DD == DD*TT
    const int q0 = qt * 128 + w * 32;

    // Q B-fragments (f16; 1/sqrt(D)*log2e pre-folded): B[n=q=lr][k=c*32+lq*8+j]
    half8 qf[2][2];
    #pragma unroll
    for (int qg = 0; qg < 2; ++qg)
        #pragma unroll
        for (int c = 0; c < 2; ++c)
            qf[qg][c] = *(const half8*)(Qh + base + (size_t)(q0 + qg * 16 + lr) * DD
                                        + c * 32 + lq * 8);

    // staging geometry (per 64-key tile each thread: 2 K half8s + 2 V half8s)
    const int kk = tid >> 3, dc = tid & 7;          // K: key 0..31, d-chunk 0..7
    u16* k_dst0 = &Ks[0][kk][dc * 8];
    const u16* k_base = Kh + base + (size_t)kk * DD + dc * 8;
    const int vd = tid >> 2, vck = tid & 3;         // V^T: d-row 0..63, slot-chunk 0..3
    u16* v_dst0 = &Vs[0][0][vd][vck * 8];           // sigma pre-applied in Vt
    const u16* v_base = Vt + base + (size_t)vd * TT + vck * 8;
    const u32* pm_base = pm + b * 1024 + lq * 8;    // [kt][lq][8]

    const int VHALF = 64 * 40;        // u16 stride between halves
    const int VBUF  = 2 * VHALF;      // u16 stride between buffers
    const int KHALF = 32 * 72;
    const int KBUF  = 64 * 72;

    union { u32 u[4]; half8 h; } one_u;
    one_u.u[0] = one_u.u[1] = one_u.u[2] = one_u.u[3] = 0x3C003C00u;   // f16 1.0 x8
    const half8 ones = one_u.h;

    // preload tile 0 into buffer 0 (straight copies)
    {
        half8 k0 = *(const half8*)k_base;
        half8 k1 = *(const half8*)(k_base + 32 * DD);
        half8 v0 = *(const half8*)v_base;
        half8 v1 = *(const half8*)(v_base + 32);
        *(half8*)k_dst0 = k0;
        *(half8*)(k_dst0 + KHALF) = k1;
        *(half8*)v_dst0 = v0;
        *(half8*)(v_dst0 + VHALF) = v1;
    }

    f32x4 o[2][5] = {};   // [qg][dg 0..3 = O d-groups, dg 4 = softmax denom l]

    const int NT = TT / 64;   // 32
    __syncthreads();

    for (int kt = 0; kt < NT; ++kt) {
        const int p = kt & 1;
        // register prefetch of next tile (overlaps compute)
        int ktn = (kt + 1 < NT) ? kt + 1 : NT - 1;
        const u16* kp = k_base + (size_t)ktn * 64 * DD;
        half8 kreg0 = *(const half8*)kp;
        half8 kreg1 = *(const half8*)(kp + 32 * DD);
        const u16* vp = v_base + ktn * 64;
        half8 vreg0 = *(const half8*)vp;
        half8 vreg1 = *(const half8*)(vp + 32);
        // current tile's packed masks (2 dwordx4 loads, zero VALU)
        u32x4 am0 = *(const u32x4*)(pm_base + kt * 32);
        u32x4 am1 = *(const u32x4*)(pm_base + kt * 32 + 4);

        // ---- K A-fragments: A[m=key=kg*16+lr][k=c*32+lq*8+j]
        half8 kf[4][2];
        #pragma unroll
        for (int kg = 0; kg < 4; ++kg)
            #pragma unroll
            for (int c = 0; c < 2; ++c)
                kf[kg][c] = *(const half8*)&Ks[p][kg * 16 + lr][c * 32 + lq * 8];

        // ---- S^T = K Q^T : lane holds keys kg*16+lq*4+r, q = qg*16+lr
        f32x4 s[4][2];
        #pragma unroll
        for (int kg = 0; kg < 4; ++kg)
            #pragma unroll
            for (int qg = 0; qg < 2; ++qg) {
                f32x4 zz = {};
                zz = __builtin_amdgcn_mfma_f32_16x16x32_f16(kf[kg][0], qf[qg][0], zz, 0, 0, 0);
                zz = __builtin_amdgcn_mfma_f32_16x16x32_f16(kf[kg][1], qf[qg][1], zz, 0, 0, 0);
                s[kg][qg] = zz;
            }

        // ---- P = exp2(S) & mask, packed in-lane into PV A-fragments (sigma layout)
        half8 pf[2][2];   // [half][qg]
        #pragma unroll
        for (int hf = 0; hf < 2; ++hf) {
            const u32x4 am = hf ? am1 : am0;
            #pragma unroll
            for (int qg = 0; qg < 2; ++qg) {
                u32x4 pk;
                pk[0] = pkh(EXP2(s[2*hf][qg][0]),   EXP2(s[2*hf][qg][1]))   & am[0];
                pk[1] = pkh(EXP2(s[2*hf][qg][2]),   EXP2(s[2*hf][qg][3]))   & am[1];
                pk[2] = pkh(EXP2(s[2*hf+1][qg][0]), EXP2(s[2*hf+1][qg][1])) & am[2];
                pk[3] = pkh(EXP2(s[2*hf+1][qg][2]), EXP2(s[2*hf+1][qg][3])) & am[3];
                pf[hf][qg] = (half8&)pk;
            }
        }

        // ---- O += P V  (per half; l via register ones B-fragment)
        #pragma unroll
        for (int hf = 0; hf < 2; ++hf) {
            #pragma unroll
            for (int dg = 0; dg < 4; ++dg) {
                half8 vf = *(const half8*)&Vs[p][hf][dg * 16 + lr][lq * 8];
                #pragma unroll
                for (int qg = 0; qg < 2; ++qg)
                    o[qg][dg] = __builtin_amdgcn_mfma_f32_16x16x32_f16(pf[hf][qg], vf, o[qg][dg], 0, 0, 0);
            }
            #pragma unroll
            for (int qg = 0; qg < 2; ++qg)
                o[qg][4] = __builtin_amdgcn_mfma_f32_16x16x32_f16(pf[hf][qg], ones, o[qg][4], 0, 0, 0);
        }

        // ---- write prefetched tile into the other buffer (straight copies)
        u16* kd = k_dst0 + (p ^ 1) * KBUF;
        *(half8*)kd = kreg0;
        *(half8*)(kd + KHALF) = kreg1;
        u16* vdst = v_dst0 + (p ^ 1) * VBUF;
        *(half8*)vdst = vreg0;
        *(half8*)(vdst + VHALF) = vreg1;
        __syncthreads();
    }

    // ---- epilogue: O / l, write fp32 [B,T,C]
    #pragma unroll
    for (int qg = 0; qg < 2; ++qg)
        #pragma unroll
        for (int r = 0; r < 4; ++r) {
            float inv = 1.f / o[qg][4][r];
            int t = q0 + qg * 16 + lq * 4 + r;
            float* op = out + (size_t)(b * TT + t) * CC + h * DD;
            #pragma unroll
            for (int dg = 0; dg < 4; ++dg)
                op[dg * 16 + lr] = o[qg][dg][r] * inv;
        }
}

// ---------------------------------------------------------------- launch
extern "C" void kernel_launch(void* const* d_in, const int* in_sizes, int n_in,
                              void* d_out, int out_size, void* d_ws, size_t ws_size,
                              hipStream_t stream) {
    const float* x    = (const float*)d_in[0];
    const int*   mask = (const int*)d_in[1];
    const float* Wq   = (const float*)d_in[2];
    const float* bq   = (const float*)d_in[3];
    const float* Wk   = (const float*)d_in[4];
    const float* bk   = (const float*)d_in[5];
    const float* Wv   = (const float*)d_in[6];
    const float* bv   = (const float*)d_in[7];
    float* out = (float*)d_out;

    // workspace layout
    u16* xb = (u16*)d_ws;                              // bf16 [8192][1024]
    u16* Wb = xb + (size_t)MM * CC;                    // bf16 [3][1024][1024]
    u16* Qh = Wb + (size_t)3 * CC * CC;                // f16 [B,H,T,D]
    u16* Kh = Qh + (size_t)MM * CC;                    // f16 [B,H,T,D]
    u16* Vt = Kh + (size_t)MM * CC;                    // f16 [B,H,D,T], sigma-permuted keys
    u32* pm = (u32*)(Vt + (size_t)MM * CC);            // packed masks [B][32][4][8]

    {
        int total = NX + 3 * NW + NPM;
        cvt_all<<<(total + 255) / 256, 256, 0, stream>>>(x, Wq, Wk, Wv, mask, xb, Wb, pm);
    }

    qkv_gemm<<<dim3(8, 64, 3), 256, 0, stream>>>(xb, Wb, bq, bk, bv, Qh, Kh, Vt);

    attn_kernel<<<dim3(TT / 128, HH, BB), 256, 0, stream>>>(Qh, Kh, Vt, pm, out);
}